// Round 3
// baseline (571.740 us; speedup 1.0000x reference)
//
#include <hip/hip_runtime.h>
#include <hip/hip_bf16.h>

typedef float f32x4 __attribute__((ext_vector_type(4)));

#define BATCH 32
#define S_LEN 4095
#define SEQ   4096
#define E_DIM 1024
#define NH    16
#define HD    64

__device__ __forceinline__ f32x4 ntload4(const float* p) {
    return __builtin_nontemporal_load((const f32x4*)p);
}
__device__ __forceinline__ void ntstore4(float* p, f32x4 v) {
    __builtin_nontemporal_store(v, (f32x4*)p);
}

// -------- kernel 0: last-valid index + fused mask/bias per batch --------
__global__ __launch_bounds__(256) void prep_kernel(const int* __restrict__ mask,
                                                   const float* __restrict__ bias,
                                                   int* __restrict__ lastbuf,
                                                   float* __restrict__ mbias) {
    int b = blockIdx.x;
    int t = threadIdx.x;
    int best = -1;
    for (int s = t; s < SEQ; s += 256) {
        int mv = mask[b * SEQ + s];
        mbias[b * SEQ + s] = mv ? bias[s] : -1.0e9f;
        if (mv) best = max(best, s);
    }
    __shared__ int red[256];
    red[t] = best;
    __syncthreads();
    for (int o = 128; o > 0; o >>= 1) {
        if (t < o) red[t] = max(red[t], red[t + o]);
        __syncthreads();
    }
    if (t == 0) lastbuf[b] = (red[0] < 0) ? (SEQ - 1) : red[0];
}

// -------- kernel 1: qkv = h @ c_attn_w + c_attn_b  (32 x 3072) --------
__global__ __launch_bounds__(256) void qkv_kernel(const float* __restrict__ hs,
                                                  const float* __restrict__ W,
                                                  const float* __restrict__ bias,
                                                  float* __restrict__ qkv) {
    int b = blockIdx.y;
    int j = blockIdx.x * 256 + threadIdx.x;
    __shared__ float h[E_DIM];
    for (int i = threadIdx.x; i < E_DIM; i += 256) h[i] = hs[b * E_DIM + i];
    __syncthreads();
    float acc = bias[j];
    #pragma unroll 8
    for (int i = 0; i < E_DIM; ++i) acc = fmaf(h[i], W[(size_t)i * 3072 + j], acc);
    qkv[b * 3072 + j] = acc;
}

// -------- kernel 2: fused cache-append + flash-decode partials (no-max softmax) --------
template <int CHUNK_T>
__global__ __launch_bounds__(256) void attn_partial_kernel(
    const float* __restrict__ kcache, const float* __restrict__ vcache,
    const float* __restrict__ mbias,
    const float* __restrict__ qkv, const int* __restrict__ lastbuf,
    float* __restrict__ newk, float* __restrict__ newv,
    float* __restrict__ pl, float* __restrict__ pctx) {
    constexpr int NCHUNK_T = SEQ / CHUNK_T;
    const int b = blockIdx.y;
    const int chunk = blockIdx.x;
    const int t = threadIdx.x;
    const int wave = t >> 6;
    const int lane = t & 63;
    const int head = wave * 4 + (lane >> 4);
    const int lig = lane & 15;            // lane within 16-lane head group
    const int col = head * HD + lig * 4;  // column in E
    const int last = lastbuf[b];

    const f32x4 q4 = *(const f32x4*)(qkv + b * 3072 + col);
    const f32x4 kn4 = *(const f32x4*)(qkv + b * 3072 + 1024 + col);
    const f32x4 vn4 = *(const f32x4*)(qkv + b * 3072 + 2048 + col);

    const float* kb = kcache + (size_t)b * S_LEN * E_DIM;
    const float* vb = vcache + (size_t)b * S_LEN * E_DIM;
    float* nkb = newk + (size_t)b * SEQ * E_DIM;
    float* nvb = newv + (size_t)b * SEQ * E_DIM;
    const float* mbb = mbias + b * SEQ;

    float l = 0.f;
    f32x4 acc = (f32x4){0.f, 0.f, 0.f, 0.f};

    const int s0 = chunk * CHUNK_T;
    const bool clean = (s0 + CHUNK_T <= S_LEN) && (last < s0 || last >= s0 + CHUNK_T);

    if (clean) {
        for (int r = 0; r < CHUNK_T; r += 4) {
            f32x4 kk[4], vv[4];
            #pragma unroll
            for (int u = 0; u < 4; ++u) {
                const size_t off = (size_t)(s0 + r + u) * E_DIM + col;
                kk[u] = ntload4(kb + off);
                vv[u] = ntload4(vb + off);
            }
            float w[4];
            #pragma unroll
            for (int u = 0; u < 4; ++u) {
                float p = kk[u][0] * q4[0] + kk[u][1] * q4[1] + kk[u][2] * q4[2] + kk[u][3] * q4[3];
                p += __shfl_xor(p, 1);
                p += __shfl_xor(p, 2);
                p += __shfl_xor(p, 4);
                p += __shfl_xor(p, 8);
                w[u] = __expf(fmaf(p, 0.125f, mbb[s0 + r + u]));
            }
            #pragma unroll
            for (int u = 0; u < 4; ++u) {
                const size_t off = (size_t)(s0 + r + u) * E_DIM + col;
                ntstore4(nkb + off, kk[u]);
                ntstore4(nvb + off, vv[u]);
            }
            #pragma unroll
            for (int u = 0; u < 4; ++u) {
                l += w[u];
                acc += vv[u] * w[u];
            }
        }
    } else {
        for (int r = 0; r < CHUNK_T; ++r) {
            const int s = s0 + r;
            f32x4 kk, vv;
            if (s == last) {
                kk = kn4; vv = vn4;
            } else if (s < S_LEN) {
                kk = ntload4(kb + (size_t)s * E_DIM + col);
                vv = ntload4(vb + (size_t)s * E_DIM + col);
            } else {
                kk = (f32x4){0.f, 0.f, 0.f, 0.f};
                vv = kk;
            }
            ntstore4(nkb + (size_t)s * E_DIM + col, kk);
            ntstore4(nvb + (size_t)s * E_DIM + col, vv);

            float p = kk[0] * q4[0] + kk[1] * q4[1] + kk[2] * q4[2] + kk[3] * q4[3];
            p += __shfl_xor(p, 1);
            p += __shfl_xor(p, 2);
            p += __shfl_xor(p, 4);
            p += __shfl_xor(p, 8);
            const float w = __expf(fmaf(p, 0.125f, mbb[s]));
            l += w;
            acc += vv * w;
        }
    }

    const int pidx = (b * NH + head) * NCHUNK_T + chunk;
    if (lig == 0) pl[pidx] = l;
    *(f32x4*)(pctx + (size_t)pidx * HD + lig * 4) = acc;
}

// -------- kernel 3: reduce chunk partials per (b,h) --------
__global__ __launch_bounds__(256) void reduce_kernel(const float* __restrict__ pl,
                                                     const float* __restrict__ pctx,
                                                     float* __restrict__ ctxout,
                                                     int nchunk) {
    const int gw = (blockIdx.x * blockDim.x + threadIdx.x) >> 6;  // (b*NH+head)
    const int lane = threadIdx.x & 63;
    if (gw >= BATCH * NH) return;
    float lacc = 0.f, cacc = 0.f;
    for (int c = 0; c < nchunk; ++c) {
        lacc += pl[gw * nchunk + c];
        cacc += pctx[(size_t)(gw * nchunk + c) * HD + lane];
    }
    ctxout[gw * HD + lane] = cacc / lacc;
}

// -------- kernel 4: out = ctx @ c_proj_w + c_proj_b --------
__global__ __launch_bounds__(256) void proj_kernel(const float* __restrict__ ctx,
                                                   const float* __restrict__ W,
                                                   const float* __restrict__ bias,
                                                   float* __restrict__ out) {
    int b = blockIdx.y;
    int j = blockIdx.x * 256 + threadIdx.x;
    __shared__ float h[E_DIM];
    for (int i = threadIdx.x; i < E_DIM; i += 256) h[i] = ctx[b * E_DIM + i];
    __syncthreads();
    float acc = bias[j];
    #pragma unroll 8
    for (int i = 0; i < E_DIM; ++i) acc = fmaf(h[i], W[(size_t)i * E_DIM + j], acc);
    out[b * E_DIM + j] = acc;
}

extern "C" void kernel_launch(void* const* d_in, const int* in_sizes, int n_in,
                              void* d_out, int out_size, void* d_ws, size_t ws_size,
                              hipStream_t stream) {
    const float* hs      = (const float*)d_in[0];
    const float* kcache  = (const float*)d_in[1];
    const float* vcache  = (const float*)d_in[2];
    const int*   mask    = (const int*)d_in[3];
    const float* attn_w  = (const float*)d_in[4];
    const float* attn_b  = (const float*)d_in[5];
    const float* proj_w  = (const float*)d_in[6];
    const float* proj_b  = (const float*)d_in[7];
    const float* bias0   = (const float*)d_in[8];  // row 0 of attn_bias

    float* out0 = (float*)d_out;                         // 32*1024
    float* newk = out0 + (size_t)BATCH * E_DIM;          // 32*4096*1024
    float* newv = newk + (size_t)BATCH * SEQ * E_DIM;

    // Workspace layout (floats): qkv | ctxbuf | mbias | pl | pctx | lastbuf
    const size_t fixed = 98304 + 32768 + (size_t)BATCH * SEQ;  // qkv+ctx+mbias
    const size_t need64 = (fixed + (size_t)512 * 64 + (size_t)512 * 64 * 64 + 32) * 4;
    const bool use64 = ws_size >= need64;
    const int NCH = use64 ? 64 : 32;

    float* ws = (float*)d_ws;
    float* qkv     = ws;
    float* ctxbuf  = qkv + 98304;
    float* mbias   = ctxbuf + 32768;
    float* pl      = mbias + (size_t)BATCH * SEQ;
    float* pctx    = pl + (size_t)512 * NCH;
    int*   lastbuf = (int*)(pctx + (size_t)512 * NCH * 64);

    prep_kernel<<<dim3(BATCH), dim3(256), 0, stream>>>(mask, bias0, lastbuf, mbias);
    qkv_kernel<<<dim3(12, BATCH), dim3(256), 0, stream>>>(hs, attn_w, attn_b, qkv);
    if (use64) {
        attn_partial_kernel<64><<<dim3(64, BATCH), dim3(256), 0, stream>>>(
            kcache, vcache, mbias, qkv, lastbuf, newk, newv, pl, pctx);
    } else {
        attn_partial_kernel<128><<<dim3(32, BATCH), dim3(256), 0, stream>>>(
            kcache, vcache, mbias, qkv, lastbuf, newk, newv, pl, pctx);
    }
    reduce_kernel<<<dim3((BATCH * NH * 64 + 255) / 256), dim3(256), 0, stream>>>(
        pl, pctx, ctxbuf, NCH);
    proj_kernel<<<dim3(4, BATCH), dim3(256), 0, stream>>>(ctxbuf, proj_w, proj_b, out0);
}

// Round 4
// 477.867 us; speedup vs baseline: 1.1964x; 1.1964x over previous
//
#include <hip/hip_runtime.h>
#include <hip/hip_bf16.h>

typedef float f32x4 __attribute__((ext_vector_type(4)));

#define BATCH 32
#define S_LEN 4095
#define SEQ   4096
#define E_DIM 1024
#define NH    16
#define HD    64

__device__ __forceinline__ f32x4 ntload4(const float* p) {
    return __builtin_nontemporal_load((const f32x4*)p);
}
__device__ __forceinline__ void ntstore4(float* p, f32x4 v) {
    __builtin_nontemporal_store(v, (f32x4*)p);
}

// -------- kernel 0: last-valid index + fused mask/bias per batch --------
__global__ __launch_bounds__(256) void prep_kernel(const int* __restrict__ mask,
                                                   const float* __restrict__ bias,
                                                   int* __restrict__ lastbuf,
                                                   float* __restrict__ mbias) {
    int b = blockIdx.x;
    int t = threadIdx.x;
    int best = -1;
    for (int s = t; s < SEQ; s += 256) {
        int mv = mask[b * SEQ + s];
        mbias[b * SEQ + s] = mv ? bias[s] : -1.0e9f;
        if (mv) best = max(best, s);
    }
    __shared__ int red[256];
    red[t] = best;
    __syncthreads();
    for (int o = 128; o > 0; o >>= 1) {
        if (t < o) red[t] = max(red[t], red[t + o]);
        __syncthreads();
    }
    if (t == 0) lastbuf[b] = (red[0] < 0) ? (SEQ - 1) : red[0];
}

// -------- kernel 1: qkv = h @ c_attn_w + c_attn_b, 4-way k-sliced --------
__global__ __launch_bounds__(256) void qkv_kernel(const float* __restrict__ hs,
                                                  const float* __restrict__ W,
                                                  const float* __restrict__ bias,
                                                  float* __restrict__ qkv) {
    const int b = blockIdx.y;
    const int jj = threadIdx.x & 63;
    const int j = blockIdx.x * 64 + jj;
    const int ksl = threadIdx.x >> 6;
    __shared__ float h[E_DIM];
    for (int i = threadIdx.x; i < E_DIM; i += 256) h[i] = hs[b * E_DIM + i];
    __syncthreads();
    float acc = 0.f;
    const int k0 = ksl * 256;
    #pragma unroll 8
    for (int k = k0; k < k0 + 256; ++k) acc = fmaf(h[k], W[(size_t)k * 3072 + j], acc);
    __shared__ float red[4][64];
    red[ksl][jj] = acc;
    __syncthreads();
    if (ksl == 0)
        qkv[b * 3072 + j] = acc + red[1][jj] + red[2][jj] + red[3][jj] + bias[j];
}

// -------- kernel 2a: K-phase — cache-append K + scores --------
template <int CHUNK_T>
__global__ __launch_bounds__(256) void attn_k_kernel(
    const float* __restrict__ kcache, const float* __restrict__ mbias,
    const float* __restrict__ qkv, const int* __restrict__ lastbuf,
    float* __restrict__ newk, float* __restrict__ scores) {
    const int b = blockIdx.y;
    const int chunk = blockIdx.x;
    const int t = threadIdx.x;
    const int wave = t >> 6;
    const int lane = t & 63;
    const int head = wave * 4 + (lane >> 4);
    const int lig = lane & 15;
    const int col = head * HD + lig * 4;
    const int last = lastbuf[b];

    const f32x4 q4 = *(const f32x4*)(qkv + b * 3072 + col);
    const f32x4 kn4 = *(const f32x4*)(qkv + b * 3072 + 1024 + col);
    const float* kb = kcache + (size_t)b * S_LEN * E_DIM;
    float* nkb = newk + (size_t)b * SEQ * E_DIM;
    const float* mbb = mbias + b * SEQ;

    __shared__ float sc[NH][CHUNK_T];
    const int s0 = chunk * CHUNK_T;
    const bool clean = (s0 + CHUNK_T <= S_LEN) && (last < s0 || last >= s0 + CHUNK_T);

    if (clean) {
        for (int r = 0; r < CHUNK_T; r += 4) {
            f32x4 kk[4];
            #pragma unroll
            for (int u = 0; u < 4; ++u)
                kk[u] = ntload4(kb + (size_t)(s0 + r + u) * E_DIM + col);
            #pragma unroll
            for (int u = 0; u < 4; ++u)
                ntstore4(nkb + (size_t)(s0 + r + u) * E_DIM + col, kk[u]);
            #pragma unroll
            for (int u = 0; u < 4; ++u) {
                float p = kk[u][0] * q4[0] + kk[u][1] * q4[1] + kk[u][2] * q4[2] + kk[u][3] * q4[3];
                p += __shfl_xor(p, 1);
                p += __shfl_xor(p, 2);
                p += __shfl_xor(p, 4);
                p += __shfl_xor(p, 8);
                if (lig == 0) sc[head][r + u] = fmaf(p, 0.125f, mbb[s0 + r + u]);
            }
        }
    } else {
        for (int r = 0; r < CHUNK_T; ++r) {
            const int s = s0 + r;
            f32x4 kk;
            if (s == last) kk = kn4;
            else if (s < S_LEN) kk = ntload4(kb + (size_t)s * E_DIM + col);
            else kk = (f32x4){0.f, 0.f, 0.f, 0.f};
            ntstore4(nkb + (size_t)s * E_DIM + col, kk);
            float p = kk[0] * q4[0] + kk[1] * q4[1] + kk[2] * q4[2] + kk[3] * q4[3];
            p += __shfl_xor(p, 1);
            p += __shfl_xor(p, 2);
            p += __shfl_xor(p, 4);
            p += __shfl_xor(p, 8);
            if (lig == 0) sc[head][r] = fmaf(p, 0.125f, mbb[s]);
        }
    }
    __syncthreads();
    for (int i = t; i < NH * CHUNK_T; i += 256) {
        const int h2 = i / CHUNK_T, r = i % CHUNK_T;
        scores[(size_t)(b * NH + h2) * SEQ + s0 + r] = sc[h2][r];
    }
}

// -------- kernel 2b: V-phase — cache-append V + weighted accumulate --------
template <int CHUNK_T>
__global__ __launch_bounds__(256) void attn_v_kernel(
    const float* __restrict__ vcache, const float* __restrict__ scores,
    const float* __restrict__ qkv, const int* __restrict__ lastbuf,
    float* __restrict__ newv, float* __restrict__ pl, float* __restrict__ pctx) {
    constexpr int NCHUNK_T = SEQ / CHUNK_T;
    const int b = blockIdx.y;
    const int chunk = blockIdx.x;
    const int t = threadIdx.x;
    const int wave = t >> 6;
    const int lane = t & 63;
    const int head = wave * 4 + (lane >> 4);
    const int lig = lane & 15;
    const int col = head * HD + lig * 4;
    const int last = lastbuf[b];

    const f32x4 vn4 = *(const f32x4*)(qkv + b * 3072 + 2048 + col);
    const float* vb = vcache + (size_t)b * S_LEN * E_DIM;
    float* nvb = newv + (size_t)b * SEQ * E_DIM;

    __shared__ float wts[NH][CHUNK_T];
    const int s0 = chunk * CHUNK_T;
    for (int i = t; i < NH * CHUNK_T; i += 256) {
        const int h2 = i / CHUNK_T, r = i % CHUNK_T;
        wts[h2][r] = __expf(scores[(size_t)(b * NH + h2) * SEQ + s0 + r]);
    }
    __syncthreads();

    float l = 0.f;
    f32x4 acc = (f32x4){0.f, 0.f, 0.f, 0.f};
    const bool clean = (s0 + CHUNK_T <= S_LEN) && (last < s0 || last >= s0 + CHUNK_T);

    if (clean) {
        for (int r = 0; r < CHUNK_T; r += 4) {
            f32x4 vv[4];
            #pragma unroll
            for (int u = 0; u < 4; ++u)
                vv[u] = ntload4(vb + (size_t)(s0 + r + u) * E_DIM + col);
            #pragma unroll
            for (int u = 0; u < 4; ++u)
                ntstore4(nvb + (size_t)(s0 + r + u) * E_DIM + col, vv[u]);
            #pragma unroll
            for (int u = 0; u < 4; ++u) {
                const float w = wts[head][r + u];
                l += w;
                acc += vv[u] * w;
            }
        }
    } else {
        for (int r = 0; r < CHUNK_T; ++r) {
            const int s = s0 + r;
            f32x4 vv;
            if (s == last) vv = vn4;
            else if (s < S_LEN) vv = ntload4(vb + (size_t)s * E_DIM + col);
            else vv = (f32x4){0.f, 0.f, 0.f, 0.f};
            ntstore4(nvb + (size_t)s * E_DIM + col, vv);
            const float w = wts[head][r];
            l += w;
            acc += vv * w;
        }
    }

    const int pidx = (b * NH + head) * NCHUNK_T + chunk;
    if (lig == 0) pl[pidx] = l;
    *(f32x4*)(pctx + (size_t)pidx * HD + lig * 4) = acc;
}

// -------- fused fallback (small workspace) --------
template <int CHUNK_T>
__global__ __launch_bounds__(256) void attn_fused_kernel(
    const float* __restrict__ kcache, const float* __restrict__ vcache,
    const float* __restrict__ mbias,
    const float* __restrict__ qkv, const int* __restrict__ lastbuf,
    float* __restrict__ newk, float* __restrict__ newv,
    float* __restrict__ pl, float* __restrict__ pctx) {
    constexpr int NCHUNK_T = SEQ / CHUNK_T;
    const int b = blockIdx.y;
    const int chunk = blockIdx.x;
    const int t = threadIdx.x;
    const int wave = t >> 6;
    const int lane = t & 63;
    const int head = wave * 4 + (lane >> 4);
    const int lig = lane & 15;
    const int col = head * HD + lig * 4;
    const int last = lastbuf[b];

    const f32x4 q4 = *(const f32x4*)(qkv + b * 3072 + col);
    const f32x4 kn4 = *(const f32x4*)(qkv + b * 3072 + 1024 + col);
    const f32x4 vn4 = *(const f32x4*)(qkv + b * 3072 + 2048 + col);
    const float* kb = kcache + (size_t)b * S_LEN * E_DIM;
    const float* vb = vcache + (size_t)b * S_LEN * E_DIM;
    float* nkb = newk + (size_t)b * SEQ * E_DIM;
    float* nvb = newv + (size_t)b * SEQ * E_DIM;
    const float* mbb = mbias + b * SEQ;

    float l = 0.f;
    f32x4 acc = (f32x4){0.f, 0.f, 0.f, 0.f};
    const int s0 = chunk * CHUNK_T;
    for (int r = 0; r < CHUNK_T; ++r) {
        const int s = s0 + r;
        f32x4 kk, vv;
        if (s == last) { kk = kn4; vv = vn4; }
        else if (s < S_LEN) {
            kk = ntload4(kb + (size_t)s * E_DIM + col);
            vv = ntload4(vb + (size_t)s * E_DIM + col);
        } else { kk = (f32x4){0.f, 0.f, 0.f, 0.f}; vv = kk; }
        ntstore4(nkb + (size_t)s * E_DIM + col, kk);
        ntstore4(nvb + (size_t)s * E_DIM + col, vv);
        float p = kk[0] * q4[0] + kk[1] * q4[1] + kk[2] * q4[2] + kk[3] * q4[3];
        p += __shfl_xor(p, 1);
        p += __shfl_xor(p, 2);
        p += __shfl_xor(p, 4);
        p += __shfl_xor(p, 8);
        const float w = __expf(fmaf(p, 0.125f, mbb[s]));
        l += w;
        acc += vv * w;
    }
    const int pidx = (b * NH + head) * NCHUNK_T + chunk;
    if (lig == 0) pl[pidx] = l;
    *(f32x4*)(pctx + (size_t)pidx * HD + lig * 4) = acc;
}

// -------- kernel 3: reduce chunk partials per (b,h) --------
__global__ __launch_bounds__(256) void reduce_kernel(const float* __restrict__ pl,
                                                     const float* __restrict__ pctx,
                                                     float* __restrict__ ctxout,
                                                     int nchunk) {
    const int gw = (blockIdx.x * blockDim.x + threadIdx.x) >> 6;
    const int lane = threadIdx.x & 63;
    if (gw >= BATCH * NH) return;
    float lacc = 0.f, cacc = 0.f;
    for (int c = 0; c < nchunk; ++c) {
        lacc += pl[gw * nchunk + c];
        cacc += pctx[(size_t)(gw * nchunk + c) * HD + lane];
    }
    ctxout[gw * HD + lane] = cacc / lacc;
}

// -------- kernel 4: out = ctx @ c_proj_w + c_proj_b, 4-way k-sliced --------
__global__ __launch_bounds__(256) void proj_kernel(const float* __restrict__ ctx,
                                                   const float* __restrict__ W,
                                                   const float* __restrict__ bias,
                                                   float* __restrict__ out) {
    const int b = blockIdx.y;
    const int jj = threadIdx.x & 63;
    const int j = blockIdx.x * 64 + jj;
    const int ksl = threadIdx.x >> 6;
    __shared__ float h[E_DIM];
    for (int i = threadIdx.x; i < E_DIM; i += 256) h[i] = ctx[b * E_DIM + i];
    __syncthreads();
    float acc = 0.f;
    const int k0 = ksl * 256;
    #pragma unroll 8
    for (int k = k0; k < k0 + 256; ++k) acc = fmaf(h[k], W[(size_t)k * E_DIM + j], acc);
    __shared__ float red[4][64];
    red[ksl][jj] = acc;
    __syncthreads();
    if (ksl == 0)
        out[b * E_DIM + j] = acc + red[1][jj] + red[2][jj] + red[3][jj] + bias[j];
}

extern "C" void kernel_launch(void* const* d_in, const int* in_sizes, int n_in,
                              void* d_out, int out_size, void* d_ws, size_t ws_size,
                              hipStream_t stream) {
    const float* hs      = (const float*)d_in[0];
    const float* kcache  = (const float*)d_in[1];
    const float* vcache  = (const float*)d_in[2];
    const int*   mask    = (const int*)d_in[3];
    const float* attn_w  = (const float*)d_in[4];
    const float* attn_b  = (const float*)d_in[5];
    const float* proj_w  = (const float*)d_in[6];
    const float* proj_b  = (const float*)d_in[7];
    const float* bias0   = (const float*)d_in[8];

    float* out0 = (float*)d_out;
    float* newk = out0 + (size_t)BATCH * E_DIM;
    float* newv = newk + (size_t)BATCH * SEQ * E_DIM;

    float* ws = (float*)d_ws;
    float* qkv    = ws;                       // 98304
    float* ctxbuf = qkv + 98304;              // 32768
    float* mbias  = ctxbuf + 32768;           // 131072

    // Split path (CHUNK=64, NCH=64): scores 2097152 + pl 32768 + pctx 2097152 + 32 ints
    const size_t base = 98304 + 32768 + 131072;
    const size_t need_split = (base + 2097152ull + 32768 + 2097152ull + 32) * 4;
    const bool use_split = ws_size >= need_split;

    prep_kernel<<<dim3(BATCH), dim3(256), 0, stream>>>(mask, bias0,
        /*lastbuf set below per path*/ (int*)(ws), mbias);  // placeholder overwritten next
    // NOTE: prep writes lastbuf; we must give it the real pointer. Re-launch with
    // correct pointer chosen per path (the placeholder call above would corrupt ws).
    // To keep determinism and avoid the placeholder entirely, we instead compute
    // pointers first and call prep exactly once below.

    (void)0;
    if (use_split) {
        float* scores  = mbias + 131072;                      // 2097152
        float* pl      = scores + 2097152;                    // 32768
        float* pctx    = pl + 32768;                          // 2097152
        int*   lastbuf = (int*)(pctx + 2097152);

        prep_kernel<<<dim3(BATCH), dim3(256), 0, stream>>>(mask, bias0, lastbuf, mbias);
        qkv_kernel<<<dim3(48, BATCH), dim3(256), 0, stream>>>(hs, attn_w, attn_b, qkv);
        attn_k_kernel<64><<<dim3(64, BATCH), dim3(256), 0, stream>>>(
            kcache, mbias, qkv, lastbuf, newk, scores);
        attn_v_kernel<64><<<dim3(64, BATCH), dim3(256), 0, stream>>>(
            vcache, scores, qkv, lastbuf, newv, pl, pctx);
        reduce_kernel<<<dim3((BATCH * NH * 64 + 255) / 256), dim3(256), 0, stream>>>(
            pl, pctx, ctxbuf, 64);
        proj_kernel<<<dim3(16, BATCH), dim3(256), 0, stream>>>(ctxbuf, proj_w, proj_b, out0);
    } else {
        float* pl      = mbias + 131072;                      // 16384 (NCH=32)
        float* pctx    = pl + 16384;                          // 1048576
        int*   lastbuf = (int*)(pctx + 1048576);

        prep_kernel<<<dim3(BATCH), dim3(256), 0, stream>>>(mask, bias0, lastbuf, mbias);
        qkv_kernel<<<dim3(48, BATCH), dim3(256), 0, stream>>>(hs, attn_w, attn_b, qkv);
        attn_fused_kernel<128><<<dim3(32, BATCH), dim3(256), 0, stream>>>(
            kcache, vcache, mbias, qkv, lastbuf, newk, newv, pl, pctx);
        reduce_kernel<<<dim3((BATCH * NH * 64 + 255) / 256), dim3(256), 0, stream>>>(
            pl, pctx, ctxbuf, 32);
        proj_kernel<<<dim3(16, BATCH), dim3(256), 0, stream>>>(ctxbuf, proj_w, proj_b, out0);
    }
}

// Round 5
// 471.056 us; speedup vs baseline: 1.2137x; 1.0145x over previous
//
#include <hip/hip_runtime.h>
#include <hip/hip_bf16.h>

typedef float f32x4 __attribute__((ext_vector_type(4)));

#define BATCH 32
#define S_LEN 4095
#define SEQ   4096
#define E_DIM 1024
#define NH    16
#define HD    64

__device__ __forceinline__ f32x4 ntload4(const float* p) {
    return __builtin_nontemporal_load((const f32x4*)p);
}
__device__ __forceinline__ void ntstore4(float* p, f32x4 v) {
    __builtin_nontemporal_store(v, (f32x4*)p);
}

// -------- kernel 0: last-valid index + fused mask/bias per batch --------
__global__ __launch_bounds__(256) void prep_kernel(const int* __restrict__ mask,
                                                   const float* __restrict__ bias,
                                                   int* __restrict__ lastbuf,
                                                   float* __restrict__ mbias) {
    int b = blockIdx.x;
    int t = threadIdx.x;
    int best = -1;
    for (int s = t; s < SEQ; s += 256) {
        int mv = mask[b * SEQ + s];
        mbias[b * SEQ + s] = mv ? bias[s] : -1.0e9f;
        if (mv) best = max(best, s);
    }
    __shared__ int red[256];
    red[t] = best;
    __syncthreads();
    for (int o = 128; o > 0; o >>= 1) {
        if (t < o) red[t] = max(red[t], red[t + o]);
        __syncthreads();
    }
    if (t == 0) lastbuf[b] = (red[0] < 0) ? (SEQ - 1) : red[0];
}

// -------- kernel 1: qkv = h @ c_attn_w + c_attn_b, 4-way k-sliced --------
__global__ __launch_bounds__(256) void qkv_kernel(const float* __restrict__ hs,
                                                  const float* __restrict__ W,
                                                  const float* __restrict__ bias,
                                                  float* __restrict__ qkv) {
    const int b = blockIdx.y;
    const int jj = threadIdx.x & 63;
    const int j = blockIdx.x * 64 + jj;
    const int ksl = threadIdx.x >> 6;
    __shared__ float h[E_DIM];
    for (int i = threadIdx.x; i < E_DIM; i += 256) h[i] = hs[b * E_DIM + i];
    __syncthreads();
    float acc = 0.f;
    const int k0 = ksl * 256;
    #pragma unroll 8
    for (int k = k0; k < k0 + 256; ++k) acc = fmaf(h[k], W[(size_t)k * 3072 + j], acc);
    __shared__ float red[4][64];
    red[ksl][jj] = acc;
    __syncthreads();
    if (ksl == 0)
        qkv[b * 3072 + j] = acc + red[1][jj] + red[2][jj] + red[3][jj] + bias[j];
}

// -------- kernel 2a: K-phase — cache-append K + exp-weights --------
template <int CHUNK_T>
__global__ __launch_bounds__(256) void attn_k_kernel(
    const float* __restrict__ kcache, const float* __restrict__ mbias,
    const float* __restrict__ qkv, const int* __restrict__ lastbuf,
    float* __restrict__ newk, float* __restrict__ wts) {
    const int b = blockIdx.y;
    const int chunk = blockIdx.x;
    const int t = threadIdx.x;
    const int wave = t >> 6;
    const int lane = t & 63;
    const int head = wave * 4 + (lane >> 4);
    const int lig = lane & 15;
    const int col = head * HD + lig * 4;
    const int last = lastbuf[b];

    const f32x4 q4 = *(const f32x4*)(qkv + b * 3072 + col);
    const f32x4 kn4 = *(const f32x4*)(qkv + b * 3072 + 1024 + col);
    const float* kb = kcache + (size_t)b * S_LEN * E_DIM;
    float* nkb = newk + (size_t)b * SEQ * E_DIM;
    const float* mbb = mbias + b * SEQ;

    __shared__ float sc[NH][CHUNK_T];
    const int s0 = chunk * CHUNK_T;
    const bool clean = (s0 + CHUNK_T <= S_LEN) && (last < s0 || last >= s0 + CHUNK_T);

    if (clean) {
        for (int r = 0; r < CHUNK_T; r += 8) {
            f32x4 kk[8];
            #pragma unroll
            for (int u = 0; u < 8; ++u)
                kk[u] = ntload4(kb + (size_t)(s0 + r + u) * E_DIM + col);
            #pragma unroll
            for (int u = 0; u < 8; ++u)
                ntstore4(nkb + (size_t)(s0 + r + u) * E_DIM + col, kk[u]);
            #pragma unroll
            for (int u = 0; u < 8; ++u) {
                float p = kk[u][0] * q4[0] + kk[u][1] * q4[1] + kk[u][2] * q4[2] + kk[u][3] * q4[3];
                p += __shfl_xor(p, 1);
                p += __shfl_xor(p, 2);
                p += __shfl_xor(p, 4);
                p += __shfl_xor(p, 8);
                if (lig == 0) sc[head][r + u] = __expf(fmaf(p, 0.125f, mbb[s0 + r + u]));
            }
        }
    } else {
        for (int r = 0; r < CHUNK_T; ++r) {
            const int s = s0 + r;
            f32x4 kk;
            if (s == last) kk = kn4;
            else if (s < S_LEN) kk = ntload4(kb + (size_t)s * E_DIM + col);
            else kk = (f32x4){0.f, 0.f, 0.f, 0.f};
            ntstore4(nkb + (size_t)s * E_DIM + col, kk);
            float p = kk[0] * q4[0] + kk[1] * q4[1] + kk[2] * q4[2] + kk[3] * q4[3];
            p += __shfl_xor(p, 1);
            p += __shfl_xor(p, 2);
            p += __shfl_xor(p, 4);
            p += __shfl_xor(p, 8);
            if (lig == 0) sc[head][r] = __expf(fmaf(p, 0.125f, mbb[s]));
        }
    }
    __syncthreads();
    for (int i = t; i < NH * CHUNK_T; i += 256) {
        const int h2 = i / CHUNK_T, r = i % CHUNK_T;
        wts[(size_t)(b * NH + h2) * SEQ + s0 + r] = sc[h2][r];
    }
}

// -------- kernel 2b: V-phase — cache-append V + weighted accumulate --------
template <int CHUNK_T>
__global__ __launch_bounds__(256) void attn_v_kernel(
    const float* __restrict__ vcache, const float* __restrict__ wts,
    const float* __restrict__ qkv, const int* __restrict__ lastbuf,
    float* __restrict__ newv, float* __restrict__ pl, float* __restrict__ pctx) {
    constexpr int NCHUNK_T = SEQ / CHUNK_T;
    const int b = blockIdx.y;
    const int chunk = blockIdx.x;
    const int t = threadIdx.x;
    const int wave = t >> 6;
    const int lane = t & 63;
    const int head = wave * 4 + (lane >> 4);
    const int lig = lane & 15;
    const int col = head * HD + lig * 4;
    const int last = lastbuf[b];

    const f32x4 vn4 = *(const f32x4*)(qkv + b * 3072 + 2048 + col);
    const float* vb = vcache + (size_t)b * S_LEN * E_DIM;
    float* nvb = newv + (size_t)b * SEQ * E_DIM;

    __shared__ float w_s[NH][CHUNK_T];
    const int s0 = chunk * CHUNK_T;
    for (int i = t; i < NH * CHUNK_T; i += 256) {
        const int h2 = i / CHUNK_T, r = i % CHUNK_T;
        w_s[h2][r] = wts[(size_t)(b * NH + h2) * SEQ + s0 + r];
    }
    __syncthreads();

    float l = 0.f;
    f32x4 acc = (f32x4){0.f, 0.f, 0.f, 0.f};
    const bool clean = (s0 + CHUNK_T <= S_LEN) && (last < s0 || last >= s0 + CHUNK_T);

    if (clean) {
        for (int r = 0; r < CHUNK_T; r += 8) {
            f32x4 vv[8];
            #pragma unroll
            for (int u = 0; u < 8; ++u)
                vv[u] = ntload4(vb + (size_t)(s0 + r + u) * E_DIM + col);
            #pragma unroll
            for (int u = 0; u < 8; ++u)
                ntstore4(nvb + (size_t)(s0 + r + u) * E_DIM + col, vv[u]);
            #pragma unroll
            for (int u = 0; u < 8; ++u) {
                const float w = w_s[head][r + u];
                l += w;
                acc += vv[u] * w;
            }
        }
    } else {
        for (int r = 0; r < CHUNK_T; ++r) {
            const int s = s0 + r;
            f32x4 vv;
            if (s == last) vv = vn4;
            else if (s < S_LEN) vv = ntload4(vb + (size_t)s * E_DIM + col);
            else vv = (f32x4){0.f, 0.f, 0.f, 0.f};
            ntstore4(nvb + (size_t)s * E_DIM + col, vv);
            const float w = w_s[head][r];
            l += w;
            acc += vv * w;
        }
    }

    const int pidx = (b * NH + head) * NCHUNK_T + chunk;
    if (lig == 0) pl[pidx] = l;
    *(f32x4*)(pctx + (size_t)pidx * HD + lig * 4) = acc;
}

// -------- fused fallback (small workspace) --------
template <int CHUNK_T>
__global__ __launch_bounds__(256) void attn_fused_kernel(
    const float* __restrict__ kcache, const float* __restrict__ vcache,
    const float* __restrict__ mbias,
    const float* __restrict__ qkv, const int* __restrict__ lastbuf,
    float* __restrict__ newk, float* __restrict__ newv,
    float* __restrict__ pl, float* __restrict__ pctx) {
    constexpr int NCHUNK_T = SEQ / CHUNK_T;
    const int b = blockIdx.y;
    const int chunk = blockIdx.x;
    const int t = threadIdx.x;
    const int wave = t >> 6;
    const int lane = t & 63;
    const int head = wave * 4 + (lane >> 4);
    const int lig = lane & 15;
    const int col = head * HD + lig * 4;
    const int last = lastbuf[b];

    const f32x4 q4 = *(const f32x4*)(qkv + b * 3072 + col);
    const f32x4 kn4 = *(const f32x4*)(qkv + b * 3072 + 1024 + col);
    const f32x4 vn4 = *(const f32x4*)(qkv + b * 3072 + 2048 + col);
    const float* kb = kcache + (size_t)b * S_LEN * E_DIM;
    const float* vb = vcache + (size_t)b * S_LEN * E_DIM;
    float* nkb = newk + (size_t)b * SEQ * E_DIM;
    float* nvb = newv + (size_t)b * SEQ * E_DIM;
    const float* mbb = mbias + b * SEQ;

    float l = 0.f;
    f32x4 acc = (f32x4){0.f, 0.f, 0.f, 0.f};
    const int s0 = chunk * CHUNK_T;
    for (int r = 0; r < CHUNK_T; ++r) {
        const int s = s0 + r;
        f32x4 kk, vv;
        if (s == last) { kk = kn4; vv = vn4; }
        else if (s < S_LEN) {
            kk = ntload4(kb + (size_t)s * E_DIM + col);
            vv = ntload4(vb + (size_t)s * E_DIM + col);
        } else { kk = (f32x4){0.f, 0.f, 0.f, 0.f}; vv = kk; }
        ntstore4(nkb + (size_t)s * E_DIM + col, kk);
        ntstore4(nvb + (size_t)s * E_DIM + col, vv);
        float p = kk[0] * q4[0] + kk[1] * q4[1] + kk[2] * q4[2] + kk[3] * q4[3];
        p += __shfl_xor(p, 1);
        p += __shfl_xor(p, 2);
        p += __shfl_xor(p, 4);
        p += __shfl_xor(p, 8);
        const float w = __expf(fmaf(p, 0.125f, mbb[s]));
        l += w;
        acc += vv * w;
    }
    const int pidx = (b * NH + head) * NCHUNK_T + chunk;
    if (lig == 0) pl[pidx] = l;
    *(f32x4*)(pctx + (size_t)pidx * HD + lig * 4) = acc;
}

// -------- kernel 3: reduce chunk partials per (b,h) --------
__global__ __launch_bounds__(256) void reduce_kernel(const float* __restrict__ pl,
                                                     const float* __restrict__ pctx,
                                                     float* __restrict__ ctxout,
                                                     int nchunk) {
    const int gw = (blockIdx.x * blockDim.x + threadIdx.x) >> 6;
    const int lane = threadIdx.x & 63;
    if (gw >= BATCH * NH) return;
    float lacc = 0.f, cacc = 0.f;
    for (int c = 0; c < nchunk; ++c) {
        lacc += pl[gw * nchunk + c];
        cacc += pctx[(size_t)(gw * nchunk + c) * HD + lane];
    }
    ctxout[gw * HD + lane] = cacc / lacc;
}

// -------- kernel 4: out = ctx @ c_proj_w + c_proj_b, 4-way k-sliced --------
__global__ __launch_bounds__(256) void proj_kernel(const float* __restrict__ ctx,
                                                   const float* __restrict__ W,
                                                   const float* __restrict__ bias,
                                                   float* __restrict__ out) {
    const int b = blockIdx.y;
    const int jj = threadIdx.x & 63;
    const int j = blockIdx.x * 64 + jj;
    const int ksl = threadIdx.x >> 6;
    __shared__ float h[E_DIM];
    for (int i = threadIdx.x; i < E_DIM; i += 256) h[i] = ctx[b * E_DIM + i];
    __syncthreads();
    float acc = 0.f;
    const int k0 = ksl * 256;
    #pragma unroll 8
    for (int k = k0; k < k0 + 256; ++k) acc = fmaf(h[k], W[(size_t)k * E_DIM + j], acc);
    __shared__ float red[4][64];
    red[ksl][jj] = acc;
    __syncthreads();
    if (ksl == 0)
        out[b * E_DIM + j] = acc + red[1][jj] + red[2][jj] + red[3][jj] + bias[j];
}

extern "C" void kernel_launch(void* const* d_in, const int* in_sizes, int n_in,
                              void* d_out, int out_size, void* d_ws, size_t ws_size,
                              hipStream_t stream) {
    const float* hs      = (const float*)d_in[0];
    const float* kcache  = (const float*)d_in[1];
    const float* vcache  = (const float*)d_in[2];
    const int*   mask    = (const int*)d_in[3];
    const float* attn_w  = (const float*)d_in[4];
    const float* attn_b  = (const float*)d_in[5];
    const float* proj_w  = (const float*)d_in[6];
    const float* proj_b  = (const float*)d_in[7];
    const float* bias0   = (const float*)d_in[8];

    float* out0 = (float*)d_out;
    float* newk = out0 + (size_t)BATCH * E_DIM;
    float* newv = newk + (size_t)BATCH * SEQ * E_DIM;

    float* ws = (float*)d_ws;
    float* qkv    = ws;                       // 98304
    float* ctxbuf = qkv + 98304;              // 32768
    float* mbias  = ctxbuf + 32768;           // 131072

    const size_t base = 98304 + 32768 + 131072;
    const size_t need_split = (base + 2097152ull + 32768 + 2097152ull + 32) * 4;
    const bool use_split = ws_size >= need_split;

    if (use_split) {
        float* wts     = mbias + 131072;                      // 2097152
        float* pl      = wts + 2097152;                       // 32768
        float* pctx    = pl + 32768;                          // 2097152
        int*   lastbuf = (int*)(pctx + 2097152);

        prep_kernel<<<dim3(BATCH), dim3(256), 0, stream>>>(mask, bias0, lastbuf, mbias);
        qkv_kernel<<<dim3(48, BATCH), dim3(256), 0, stream>>>(hs, attn_w, attn_b, qkv);
        attn_k_kernel<64><<<dim3(64, BATCH), dim3(256), 0, stream>>>(
            kcache, mbias, qkv, lastbuf, newk, wts);
        attn_v_kernel<64><<<dim3(64, BATCH), dim3(256), 0, stream>>>(
            vcache, wts, qkv, lastbuf, newv, pl, pctx);
        reduce_kernel<<<dim3((BATCH * NH * 64 + 255) / 256), dim3(256), 0, stream>>>(
            pl, pctx, ctxbuf, 64);
        proj_kernel<<<dim3(16, BATCH), dim3(256), 0, stream>>>(ctxbuf, proj_w, proj_b, out0);
    } else {
        float* pl      = mbias + 131072;                      // 16384 (NCH=32)
        float* pctx    = pl + 16384;                          // 1048576
        int*   lastbuf = (int*)(pctx + 1048576);

        prep_kernel<<<dim3(BATCH), dim3(256), 0, stream>>>(mask, bias0, lastbuf, mbias);
        qkv_kernel<<<dim3(48, BATCH), dim3(256), 0, stream>>>(hs, attn_w, attn_b, qkv);
        attn_fused_kernel<128><<<dim3(32, BATCH), dim3(256), 0, stream>>>(
            kcache, vcache, mbias, qkv, lastbuf, newk, newv, pl, pctx);
        reduce_kernel<<<dim3((BATCH * NH * 64 + 255) / 256), dim3(256), 0, stream>>>(
            pl, pctx, ctxbuf, 32);
        proj_kernel<<<dim3(16, BATCH), dim3(256), 0, stream>>>(ctxbuf, proj_w, proj_b, out0);
    }
}